// Round 10
// baseline (227.837 us; speedup 1.0000x reference)
//
#include <hip/hip_runtime.h>
#include <cstdint>
#include <cstddef>

typedef __bf16 bf16_t;
typedef __bf16 bf16x8 __attribute__((ext_vector_type(8)));
typedef __bf16 bf16x4 __attribute__((ext_vector_type(4)));
typedef float floatx4 __attribute__((ext_vector_type(4)));

#define MFMA_BF16_16x16x32(a, b, c) \
  __builtin_amdgcn_mfma_f32_16x16x32_bf16((a), (b), (c), 0, 0, 0)

static constexpr int kT = 2048;   // sequence length
static constexpr int kDM = 1024;  // d_model
static constexpr int kNH = 16;
static constexpr int kDH = 64;
static constexpr float kLog2e = 1.4426950408889634f;
static constexpr int kPS = 140;   // P row stride (bank-conflict-free, R3+)

// Async global->LDS, 16B per lane.
__device__ __forceinline__ void gl_lds16(const bf16_t* g, bf16_t* l) {
  __builtin_amdgcn_global_load_lds(
      (const __attribute__((address_space(1))) void*)g,
      (__attribute__((address_space(3))) void*)l, 16, 0, 0);
}

// ---------------------------------------------------------------------------
// Inline dtype probe: scan first 128 u16 of x (same for all threads -> no
// reduction needed). fp32 data -> ~54/128 wild exponents; bf16 -> ~0.
// Returns 1 if inputs are bf16.
// ---------------------------------------------------------------------------
__device__ __forceinline__ int detect_bf16(const unsigned short* __restrict__ xv) {
  int bad = 0;
  for (int i = 0; i < 128; i++) {
    const unsigned e = (xv[i] >> 7) & 0xFF;
    if (e == 0xFF || (e != 0 && (e < 107 || e > 147))) bad++;
  }
  return bad < 13;
}

// ---------------------------------------------------------------------------
// x -> bf16 contiguous copy (from bf16 or fp32 source per inline flag).
// ---------------------------------------------------------------------------
__global__ __launch_bounds__(256) void convert_x(
    const void* __restrict__ src, bf16_t* __restrict__ dst, int n) {
  const int f = detect_bf16((const unsigned short*)src);
  const int i = (blockIdx.x * 256 + threadIdx.x) * 8;
  if (i >= n) return;
  if (f) {
    *(bf16x8*)(dst + i) = *(const bf16x8*)((const bf16_t*)src + i);
  } else {
    const float* s = (const float*)src + i;
    bf16x8 v;
#pragma unroll
    for (int j = 0; j < 8; j++) v[j] = (bf16_t)s[j];
    *(bf16x8*)(dst + i) = v;
  }
}

// ---------------------------------------------------------------------------
// Weight convert+transpose: W [k][n] (bf16 or fp32) -> W^T [n][k] bf16.
// grid (16,16,4).
// ---------------------------------------------------------------------------
__global__ __launch_bounds__(256) void convert_transpose_w(
    const void* __restrict__ xsrc, const void* __restrict__ w0,
    const void* __restrict__ w1, const void* __restrict__ w2,
    const void* __restrict__ w3, bf16_t* __restrict__ out_base) {
  const int f = detect_bf16((const unsigned short*)xsrc);
  const void* src = (blockIdx.z == 0) ? w0
                  : (blockIdx.z == 1) ? w1
                  : (blockIdx.z == 2) ? w2 : w3;
  bf16_t* dst = out_base + (size_t)blockIdx.z * (kDM * kDM);
  __shared__ bf16_t tile[64][65];
  const int tx = threadIdx.x & 63;
  const int ty = threadIdx.x >> 6;
  const int x0 = blockIdx.x * 64;
  const int y0 = blockIdx.y * 64;
#pragma unroll
  for (int r = 0; r < 64; r += 4) {
    const size_t idx = (size_t)(y0 + ty + r) * kDM + x0 + tx;
    tile[ty + r][tx] =
        f ? ((const bf16_t*)src)[idx] : (bf16_t)((const float*)src)[idx];
  }
  __syncthreads();
#pragma unroll
  for (int r = 0; r < 64; r += 4)
    dst[(size_t)(x0 + ty + r) * kDM + y0 + tx] = tile[tx][ty + r];
}

// ---------------------------------------------------------------------------
// 128x128 GEMM core, B^T form, BK=32, m97 structure (R7-verified).
// ---------------------------------------------------------------------------
__device__ __forceinline__ void gemm_core_128x128(
    const bf16_t* __restrict__ A, const bf16_t* __restrict__ Bt, int K,
    bf16_t* __restrict__ sA, bf16_t* __restrict__ sB, floatx4 acc[4][4]) {
  const int tid = threadIdx.x;
  const int lane = tid & 63;
  const int w = tid >> 6;
  const int quad = lane >> 4;
  const int l16 = lane & 15;
  const int wm = w >> 1;
  const int wn = w & 1;
  const int sr = tid >> 2;
  const int sc = (tid & 3) * 8;
  const int wbase = w * 512;

  const bf16_t* pa0 = A + (size_t)sr * K + sc;
  const bf16_t* pa1 = A + (size_t)(sr + 64) * K + sc;
  const bf16_t* pb0 = Bt + (size_t)sr * K + sc;
  const bf16_t* pb1 = Bt + (size_t)(sr + 64) * K + sc;

  for (int kk = 0; kk < K; kk += 32) {
    __syncthreads();
    gl_lds16(pa0 + kk, sA + wbase);
    gl_lds16(pa1 + kk, sA + 2048 + wbase);
    gl_lds16(pb0 + kk, sB + wbase);
    gl_lds16(pb1 + kk, sB + 2048 + wbase);
    __syncthreads();
    bf16x8 af[4], bf[4];
#pragma unroll
    for (int mi = 0; mi < 4; mi++)
      af[mi] = *(const bf16x8*)(sA + (wm * 64 + mi * 16 + l16) * 32 + quad * 8);
#pragma unroll
    for (int ni = 0; ni < 4; ni++)
      bf[ni] = *(const bf16x8*)(sB + (wn * 64 + ni * 16 + l16) * 32 + quad * 8);
#pragma unroll
    for (int mi = 0; mi < 4; mi++)
#pragma unroll
      for (int ni = 0; ni < 4; ni++)
        acc[mi][ni] = MFMA_BF16_16x16x32(af[mi], bf[ni], acc[mi][ni]);
  }
}

// ---------------------------------------------------------------------------
// 64x128 GEMM core, BK=32 (out_proj, R7-verified).
// ---------------------------------------------------------------------------
__device__ __forceinline__ void gemm_core_64x128(
    const bf16_t* __restrict__ A, const bf16_t* __restrict__ Bt, int K,
    bf16_t* __restrict__ sA, bf16_t* __restrict__ sB, floatx4 acc[2][4]) {
  const int tid = threadIdx.x;
  const int lane = tid & 63;
  const int w = tid >> 6;
  const int quad = lane >> 4;
  const int l16 = lane & 15;
  const int wm = w >> 1;
  const int wn = w & 1;
  const int sr = tid >> 2;
  const int sc = (tid & 3) * 8;
  const int wbase = w * 512;

  const bf16_t* pa = A + (size_t)sr * K + sc;
  const bf16_t* pb0 = Bt + (size_t)sr * K + sc;
  const bf16_t* pb1 = Bt + (size_t)(sr + 64) * K + sc;

  for (int kk = 0; kk < K; kk += 32) {
    __syncthreads();
    gl_lds16(pa + kk, sA + wbase);
    gl_lds16(pb0 + kk, sB + wbase);
    gl_lds16(pb1 + kk, sB + 2048 + wbase);
    __syncthreads();
    bf16x8 af[2], bf[4];
#pragma unroll
    for (int mi = 0; mi < 2; mi++)
      af[mi] = *(const bf16x8*)(sA + (wm * 32 + mi * 16 + l16) * 32 + quad * 8);
#pragma unroll
    for (int ni = 0; ni < 4; ni++)
      bf[ni] = *(const bf16x8*)(sB + (wn * 64 + ni * 16 + l16) * 32 + quad * 8);
#pragma unroll
    for (int mi = 0; mi < 2; mi++)
#pragma unroll
      for (int ni = 0; ni < 4; ni++)
        acc[mi][ni] = MFMA_BF16_16x16x32(af[mi], bf[ni], acc[mi][ni]);
  }
}

// ---------------------------------------------------------------------------
// QKV projection. Outputs in MFMA fragment order (R7-verified):
//   Qf[bh][task][kh][lane][8], Kf[bh][kt][kh][ni][lane][8],
//   Vf[bh][kt][ks][nd][lane][8].
// grid = (32 m, 8 n, 3): consecutive blocks share the same Wt slice (L2).
// ---------------------------------------------------------------------------
__global__ __launch_bounds__(256) void qkv_proj(
    const bf16_t* __restrict__ x, const bf16_t* __restrict__ wt_base,
    bf16_t* __restrict__ Qf, bf16_t* __restrict__ Kf, bf16_t* __restrict__ Vf) {
  __shared__ bf16_t smem[8704];  // staging 8192; epilogue 4 waves x 2176
  const int m0 = blockIdx.x * 128;
  const int n0 = blockIdx.y * 128;
  const int which = blockIdx.z;
  const bf16_t* Bt = wt_base + (size_t)which * (kDM * kDM);

  floatx4 acc[4][4];
  const floatx4 zero4 = {0.f, 0.f, 0.f, 0.f};
#pragma unroll
  for (int mi = 0; mi < 4; mi++)
#pragma unroll
    for (int ni = 0; ni < 4; ni++) acc[mi][ni] = zero4;

  gemm_core_128x128(x + (size_t)m0 * kDM, Bt + (size_t)n0 * kDM, kDM,
                    smem, smem + 4096, acc);

  const int tid = threadIdx.x;
  const int lane = tid & 63, w = tid >> 6;
  const int quad = lane >> 4, l16 = lane & 15;
  const int wm = w >> 1, wn = w & 1;
  const int h = (n0 + wn * 64) >> 6;  // this wave's head

  if (which == 2) {
    // V: direct stores (512B-coalesced per instruction)
#pragma unroll
    for (int mi = 0; mi < 4; mi++) {
#pragma unroll
      for (int ni = 0; ni < 4; ni++) {
        const int n = n0 + wn * 64 + ni * 16 + l16;
        const int d = n & 63;
        const int ndv = d >> 4, l16v = d & 15;
        const int m = m0 + wm * 64 + mi * 16 + quad * 4;  // reg 0 row
        const int b = m >> 11, t0 = m & (kT - 1);
        const int kt = t0 >> 7, ks = (t0 >> 5) & 3, quadv = (t0 >> 3) & 3;
        const int eb = t0 & 4;
        bf16x4 v;
        v[0] = (bf16_t)acc[mi][ni][0];
        v[1] = (bf16_t)acc[mi][ni][1];
        v[2] = (bf16_t)acc[mi][ni][2];
        v[3] = (bf16_t)acc[mi][ni][3];
        *(bf16x4*)(Vf + (((((size_t)(b * kNH + h) * 16 + kt) * 4 + ks) * 4 +
                          ndv) * 64 + quadv * 16 + l16v) * 8 + eb) = v;
      }
    }
  } else {
    __syncthreads();  // staging-LDS readers done before reuse
    bf16_t* Out = (which == 0) ? Qf : Kf;
    bf16_t* Lw = smem + w * 2176;  // wave-private: 32 rows x 68 stride
#pragma unroll
    for (int pass = 0; pass < 2; pass++) {
#pragma unroll
      for (int mi2 = 0; mi2 < 2; mi2++) {
        const int mi = pass * 2 + mi2;
#pragma unroll
        for (int ni = 0; ni < 4; ni++)
#pragma unroll
          for (int reg = 0; reg < 4; reg++)
            Lw[(mi2 * 16 + quad * 4 + reg) * 68 + ni * 16 + l16] =
                (bf16_t)acc[mi][ni][reg];
      }
      __asm volatile("s_waitcnt lgkmcnt(0)" ::: "memory");
      const int tb = m0 + wm * 64 + pass * 32;  // uniform
#pragma unroll
      for (int i = 0; i < 4; i++) {
        const int khf = i >> 1, nifr = i & 1;
        const bf16x8 v = *(const bf16x8*)(Lw + (nifr * 16 + l16) * 68 +
                                          khf * 32 + quad * 8);
        const int t0 = tb + nifr * 16;  // uniform, multiple of 16
        const int b = t0 >> 11, tt = t0 & (kT - 1);
        size_t base;
        if (which == 0) {
          base = (((size_t)(b * kNH + h) * 128 + (tt >> 4)) * 2 + khf) * 512;
        } else {
          const int kt = tt >> 7, nif = (tt & 127) >> 4;
          base = ((((size_t)(b * kNH + h) * 16 + kt) * 2 + khf) * 8 + nif) * 512;
        }
        *(bf16x8*)(Out + base + lane * 8) = v;  // 1KB contiguous per wave
      }
    }
  }
}

// ---------------------------------------------------------------------------
// Attention pair-task: TWO adjacent tasks (tA, tA+1; same group -> identical
// k-range) processed per iteration sharing one kf/vf load set: halves L2
// traffic per flop. Static-max softmax p = exp2(s*C1 - 16) (exact split-K
// merge). V loaded in two 8-frag halves to cap VGPR. Wave-private P rows:
// A -> rows 0..15 of Pw, B -> rows 16..31.
// ---------------------------------------------------------------------------
__device__ __forceinline__ void attn_pair(
    int tA, int k0, int k1, int nkt, int lane, int l16, int quad,
    const bf16_t* __restrict__ Qb, const bf16_t* __restrict__ Kbf,
    const bf16_t* __restrict__ Vbf, bf16_t* __restrict__ Pw,
    floatx4 ofA[4], floatx4 ofB[4], float lA[4], float lB[4]) {
  const int tB = tA + 1;
  const float C1 = 0.125f * kLog2e;
  const floatx4 zero4 = {0.f, 0.f, 0.f, 0.f};
#pragma unroll
  for (int nd = 0; nd < 4; nd++) { ofA[nd] = zero4; ofB[nd] = zero4; }
#pragma unroll
  for (int r = 0; r < 4; r++) { lA[r] = 0.f; lB[r] = 0.f; }
  if (k0 >= k1) return;

  bf16x8 qfA[2], qfB[2];
#pragma unroll
  for (int kh = 0; kh < 2; kh++) {
    qfA[kh] = *(const bf16x8*)(Qb + ((size_t)tA * 2 + kh) * 512 + lane * 8);
    qfB[kh] = *(const bf16x8*)(Qb + ((size_t)tB * 2 + kh) * 512 + lane * 8);
  }

  bf16x8 kf[16];
#pragma unroll
  for (int fi = 0; fi < 16; fi++)
    kf[fi] = *(const bf16x8*)(Kbf + ((size_t)k0 * 16 + fi) * 512 + lane * 8);

  for (int kt = k0; kt < k1; kt++) {
    const int kbase = kt * 128;
    const bool diag = (kt == nkt - 1);
    const bf16_t* vp = Vbf + (size_t)kt * 16 * 512 + lane * 8;
    // ---- S_A ----
    floatx4 sf[8];
#pragma unroll
    for (int ni = 0; ni < 8; ni++) sf[ni] = zero4;
#pragma unroll
    for (int kh = 0; kh < 2; kh++)
#pragma unroll
      for (int ni = 0; ni < 8; ni++)
        sf[ni] = MFMA_BF16_16x16x32(qfA[kh], kf[kh * 8 + ni], sf[ni]);
    // early V half-0 issue (covered by softmax_A + S_B)
    bf16x8 vf0[8];
#pragma unroll
    for (int fi = 0; fi < 8; fi++)
      vf0[fi] = *(const bf16x8*)(vp + (size_t)fi * 512);
    // ---- softmax A -> P rows 0..15 ----
#pragma unroll
    for (int reg = 0; reg < 4; reg++) {
      const int row_l = quad * 4 + reg;
      const int row_g = tA * 16 + row_l;
      float rsum = 0.f;
#pragma unroll
      for (int ni = 0; ni < 8; ni++) {
        float s = sf[ni][reg] * C1 - 16.f;
        if (diag && (kbase + ni * 16 + l16 > row_g)) s = -3.0e38f;
        const float p = exp2f(s);
        rsum += p;
        Pw[row_l * kPS + ni * 16 + l16] = (bf16_t)p;
      }
      lA[reg] += rsum;
    }
    // ---- S_B (kf still live) ----
#pragma unroll
    for (int ni = 0; ni < 8; ni++) sf[ni] = zero4;
#pragma unroll
    for (int kh = 0; kh < 2; kh++)
#pragma unroll
      for (int ni = 0; ni < 8; ni++)
        sf[ni] = MFMA_BF16_16x16x32(qfB[kh], kf[kh * 8 + ni], sf[ni]);
    // ---- prefetch next K tile (covered by softmax_B + PV) ----
    const int ktp = (kt + 1 < k1) ? kt + 1 : kt;
    const bf16_t* kp = Kbf + (size_t)ktp * 16 * 512 + lane * 8;
#pragma unroll
    for (int fi = 0; fi < 16; fi++)
      kf[fi] = *(const bf16x8*)(kp + (size_t)fi * 512);
    // ---- softmax B -> P rows 16..31 ----
#pragma unroll
    for (int reg = 0; reg < 4; reg++) {
      const int row_l = quad * 4 + reg;
      const int row_g = tB * 16 + row_l;
      float rsum = 0.f;
#pragma unroll
      for (int ni = 0; ni < 8; ni++) {
        float s = sf[ni][reg] * C1 - 16.f;
        if (diag && (kbase + ni * 16 + l16 > row_g)) s = -3.0e38f;
        const float p = exp2f(s);
        rsum += p;
        Pw[(16 + row_l) * kPS + ni * 16 + l16] = (bf16_t)p;
      }
      lB[reg] += rsum;
    }
    __asm volatile("s_waitcnt lgkmcnt(0)" ::: "memory");
    // ---- V half-1 issue (covered by PV ks 0,1) ----
    bf16x8 vf1[8];
#pragma unroll
    for (int fi = 0; fi < 8; fi++)
      vf1[fi] = *(const bf16x8*)(vp + (size_t)(8 + fi) * 512);
    // ---- O += P V for both tasks, shared vf ----
#pragma unroll
    for (int ks = 0; ks < 4; ks++) {
      const bf16x8 afA = *(const bf16x8*)(Pw + l16 * kPS + ks * 32 + quad * 8);
      const bf16x8 afB =
          *(const bf16x8*)(Pw + (16 + l16) * kPS + ks * 32 + quad * 8);
#pragma unroll
      for (int nd = 0; nd < 4; nd++) {
        const bf16x8 vv = (ks < 2) ? vf0[ks * 4 + nd] : vf1[(ks - 2) * 4 + nd];
        ofA[nd] = MFMA_BF16_16x16x32(afA, vv, ofA[nd]);
        ofB[nd] = MFMA_BF16_16x16x32(afB, vv, ofB[nd]);
      }
    }
  }
}

// ---------------------------------------------------------------------------
// Flash attention (causal). grid = (32 bh, 16) = 512 blocks = exactly 2/CU
// (LDS 58.4KB). Wave (pairsel, half): pair u = by*2+pairsel, phases do pairs
// {u, 63-u} (uniform 17 k-iters per half-pair; 8-9 per wave). Split-K halves
// merge exactly via padded LDS buffers (static-max softmax).
// ---------------------------------------------------------------------------
__global__ __launch_bounds__(256, 2) void attn_fused(
    const bf16_t* __restrict__ Qf, const bf16_t* __restrict__ Kf,
    const bf16_t* __restrict__ Vf, bf16_t* __restrict__ Z) {
  __shared__ bf16_t Ps[128 * kPS];   // 35840 B
  __shared__ float MO[2][2][64][17]; // 17408 B (padded stride)
  __shared__ float ML[2][2][64][5];  // 5120 B
  const int bh = blockIdx.x;
  const int tid = threadIdx.x;
  const int lane = tid & 63;
  const int w = tid >> 6;
  const int quad = lane >> 4;
  const int l16 = lane & 15;
  const int pairsel = w >> 1;
  const int half = w & 1;
  const int u = blockIdx.y * 2 + pairsel;  // 0..31
  bf16_t* Pw = Ps + (w * 32) * kPS;

  const bf16_t* Qb = Qf + (size_t)bh * kT * kDH;
  const bf16_t* Kbf = Kf + (size_t)bh * kT * kDH;
  const bf16_t* Vbf = Vf + (size_t)bh * kT * kDH;
  const int b = bh >> 4, h = bh & 15;

#pragma unroll
  for (int ts = 0; ts < 2; ts++) {
    const int pu = ts ? (63 - u) : u;   // pair index 0..63
    const int tA = pu * 2;              // tasks tA, tA+1 (same group)
    const int nkt = (tA >> 3) + 1;
    const int h0 = (nkt + 1) >> 1;
    const int k0 = half ? h0 : 0;
    const int k1 = half ? nkt : h0;
    floatx4 ofA[4], ofB[4];
    float lA[4], lB[4];
    attn_pair(tA, k0, k1, nkt, lane, l16, quad, Qb, Kbf, Vbf, Pw,
              ofA, ofB, lA, lB);
    if (half == 1) {
#pragma unroll
      for (int nd = 0; nd < 4; nd++)
#pragma unroll
        for (int reg = 0; reg < 4; reg++) {
          MO[pairsel][0][lane][nd * 4 + reg] = ofA[nd][reg];
          MO[pairsel][1][lane][nd * 4 + reg] = ofB[nd][reg];
        }
#pragma unroll
      for (int reg = 0; reg < 4; reg++) {
        ML[pairsel][0][lane][reg] = lA[reg];
        ML[pairsel][1][lane][reg] = lB[reg];
      }
    }
    __syncthreads();
    if (half == 0) {
#pragma unroll
      for (int nd = 0; nd < 4; nd++)
#pragma unroll
        for (int reg = 0; reg < 4; reg++) {
          ofA[nd][reg] += MO[pairsel][0][lane][nd * 4 + reg];
          ofB[nd][reg] += MO[pairsel][1][lane][nd * 4 + reg];
        }
#pragma unroll
      for (int reg = 0; reg < 4; reg++) {
        lA[reg] += ML[pairsel][0][lane][reg];
        lB[reg] += ML[pairsel][1][lane][reg];
#pragma unroll
        for (int off = 1; off < 16; off <<= 1) {
          lA[reg] += __shfl_xor(lA[reg], off, 64);
          lB[reg] += __shfl_xor(lB[reg], off, 64);
        }
      }
#pragma unroll
      for (int t2 = 0; t2 < 2; t2++) {
        const int q0 = (tA + t2) * 16;
#pragma unroll
        for (int reg = 0; reg < 4; reg++) {
          const int t = q0 + quad * 4 + reg;
          const float inv = 1.f / (t2 ? lB[reg] : lA[reg]);
#pragma unroll
          for (int nd = 0; nd < 4; nd++) {
            const int col = h * 64 + nd * 16 + l16;
            const float ov = t2 ? ofB[nd][reg] : ofA[nd][reg];
            Z[(size_t)(b * kT + t) * kDM + col] = (bf16_t)(ov * inv);
          }
        }
      }
    }
    __syncthreads();  // MO/ML safe to reuse for next phase
  }
}

// ---------------------------------------------------------------------------
// Output projection: Z [4096][1024] @ Wout^T -> out (dtype per inline flag).
// 64x128 tiles, BK=32: grid (64 m, 8 n) = 512 blocks (m-fast for Wt L2).
// ---------------------------------------------------------------------------
__global__ __launch_bounds__(256) void out_proj(
    const bf16_t* __restrict__ Zin, const bf16_t* __restrict__ WtO,
    void* __restrict__ out, const void* __restrict__ xsrc) {
  __shared__ bf16_t smem[6144];  // sA 2048 + sB 4096
  const int f = detect_bf16((const unsigned short*)xsrc);
  const int m0 = blockIdx.x * 64;
  const int n0 = blockIdx.y * 128;
  floatx4 acc[2][4];
  const floatx4 zero4 = {0.f, 0.f, 0.f, 0.f};
#pragma unroll
  for (int mi = 0; mi < 2; mi++)
#pragma unroll
    for (int ni = 0; ni < 4; ni++) acc[mi][ni] = zero4;

  gemm_core_64x128(Zin + (size_t)m0 * kDM, WtO + (size_t)n0 * kDM, kDM,
                   smem, smem + 2048, acc);

  const int tid = threadIdx.x;
  const int lane = tid & 63, w = tid >> 6;
  const int quad = lane >> 4, l16 = lane & 15;
  const int wm = w >> 1, wn = w & 1;
#pragma unroll
  for (int mi = 0; mi < 2; mi++) {
#pragma unroll
    for (int ni = 0; ni < 4; ni++) {
      const int n = n0 + wn * 64 + ni * 16 + l16;
#pragma unroll
      for (int reg = 0; reg < 4; reg++) {
        const int m = m0 + wm * 32 + mi * 16 + quad * 4 + reg;
        if (f) {
          ((bf16_t*)out)[(size_t)m * kDM + n] = (bf16_t)acc[mi][ni][reg];
        } else {
          ((float*)out)[(size_t)m * kDM + n] = acc[mi][ni][reg];
        }
      }
    }
  }
}

// ---------------------------------------------------------------------------
// Workspace layout (bf16 elements):
//   [0,4M)   : W^T q,k,v,o   (4 x 1M)
//   [4M,8M)  : xb (x as bf16)
//   [8M,12M) : Qf fragment-order
//   [12M,16M): Kf fragment-order
//   [16M,20M): Vf fragment-order
//   [20M,24M): Z  [B][T][H*D]
// ---------------------------------------------------------------------------
extern "C" void kernel_launch(void* const* d_in, const int* in_sizes, int n_in,
                              void* d_out, int out_size, void* d_ws,
                              size_t ws_size, hipStream_t stream) {
  const void* x = d_in[0];
  const void* Wq = d_in[1];
  const void* Wk = d_in[2];
  const void* Wv = d_in[3];
  const void* Wo = d_in[4];
  bf16_t* ws = (bf16_t*)d_ws;
  const size_t MEG = 1024 * 1024;
  bf16_t* wt = ws;
  bf16_t* xb = ws + 4 * MEG;
  bf16_t* Qf = ws + 8 * MEG;
  bf16_t* Kf = ws + 12 * MEG;
  bf16_t* Vf = ws + 16 * MEG;
  bf16_t* Z = ws + 20 * MEG;

  convert_x<<<2048, 256, 0, stream>>>(x, xb, 4 * (int)MEG);
  convert_transpose_w<<<dim3(16, 16, 4), 256, 0, stream>>>(x, Wq, Wk, Wv, Wo,
                                                           wt);
  qkv_proj<<<dim3(32, 8, 3), 256, 0, stream>>>(xb, wt, Qf, Kf, Vf);
  attn_fused<<<dim3(32, 16), 256, 0, stream>>>(Qf, Kf, Vf, Z);
  out_proj<<<dim3(64, 8), 256, 0, stream>>>(Z, wt + 3 * MEG, d_out, x);
}

// Round 11
// 187.812 us; speedup vs baseline: 1.2131x; 1.2131x over previous
//
#include <hip/hip_runtime.h>
#include <cstdint>
#include <cstddef>

typedef __bf16 bf16_t;
typedef __bf16 bf16x8 __attribute__((ext_vector_type(8)));
typedef __bf16 bf16x4 __attribute__((ext_vector_type(4)));
typedef float floatx4 __attribute__((ext_vector_type(4)));

#define MFMA_BF16_16x16x32(a, b, c) \
  __builtin_amdgcn_mfma_f32_16x16x32_bf16((a), (b), (c), 0, 0, 0)

static constexpr int kT = 2048;   // sequence length
static constexpr int kDM = 1024;  // d_model
static constexpr int kNH = 16;
static constexpr int kDH = 64;
static constexpr float kLog2e = 1.4426950408889634f;
static constexpr int kPS = 140;   // P row stride (bank-conflict-free, R3+)

// Async global->LDS, 16B per lane.
__device__ __forceinline__ void gl_lds16(const bf16_t* g, bf16_t* l) {
  __builtin_amdgcn_global_load_lds(
      (const __attribute__((address_space(1))) void*)g,
      (__attribute__((address_space(3))) void*)l, 16, 0, 0);
}

// ---------------------------------------------------------------------------
// Input dtype probe (flag=1 -> bf16 inputs, 0 -> fp32). Verified R2.
// ---------------------------------------------------------------------------
__global__ __launch_bounds__(256) void detect_dtype(
    const unsigned short* __restrict__ xv, int* __restrict__ flagp) {
  __shared__ int bad_s[256];
  int bad = 0;
  for (int i = threadIdx.x; i < 8192; i += 256) {
    const unsigned e = (xv[i] >> 7) & 0xFF;
    if (e == 0xFF || (e != 0 && (e < 107 || e > 147))) bad++;
  }
  bad_s[threadIdx.x] = bad;
  __syncthreads();
  for (int s = 128; s > 0; s >>= 1) {
    if (threadIdx.x < s) bad_s[threadIdx.x] += bad_s[threadIdx.x + s];
    __syncthreads();
  }
  if (threadIdx.x == 0) *flagp = (bad_s[0] * 10 < 8192) ? 1 : 0;
}

// ---------------------------------------------------------------------------
// x -> bf16 contiguous copy (from bf16 or fp32 source per flag).
// ---------------------------------------------------------------------------
__global__ __launch_bounds__(256) void convert_x(
    const void* __restrict__ src, bf16_t* __restrict__ dst,
    const int* __restrict__ flagp, int n) {
  const int f = *flagp;
  const int i = (blockIdx.x * 256 + threadIdx.x) * 8;
  if (i >= n) return;
  if (f) {
    *(bf16x8*)(dst + i) = *(const bf16x8*)((const bf16_t*)src + i);
  } else {
    const float* s = (const float*)src + i;
    bf16x8 v;
#pragma unroll
    for (int j = 0; j < 8; j++) v[j] = (bf16_t)s[j];
    *(bf16x8*)(dst + i) = v;
  }
}

// ---------------------------------------------------------------------------
// Weight convert+transpose: W [k][n] (bf16 or fp32) -> W^T [n][k] bf16.
// ---------------------------------------------------------------------------
__global__ __launch_bounds__(256) void convert_transpose_w(
    const void* __restrict__ w0, const void* __restrict__ w1,
    const void* __restrict__ w2, const void* __restrict__ w3,
    bf16_t* __restrict__ out_base, const int* __restrict__ flagp) {
  const int f = *flagp;
  const void* src = (blockIdx.z == 0) ? w0
                  : (blockIdx.z == 1) ? w1
                  : (blockIdx.z == 2) ? w2 : w3;
  bf16_t* dst = out_base + (size_t)blockIdx.z * (kDM * kDM);
  __shared__ bf16_t tile[64][65];
  const int tx = threadIdx.x & 63;
  const int ty = threadIdx.x >> 6;
  const int x0 = blockIdx.x * 64;
  const int y0 = blockIdx.y * 64;
#pragma unroll
  for (int r = 0; r < 64; r += 4) {
    const size_t idx = (size_t)(y0 + ty + r) * kDM + x0 + tx;
    tile[ty + r][tx] =
        f ? ((const bf16_t*)src)[idx] : (bf16_t)((const float*)src)[idx];
  }
  __syncthreads();
#pragma unroll
  for (int r = 0; r < 64; r += 4)
    dst[(size_t)(x0 + ty + r) * kDM + y0 + tx] = tile[tx][ty + r];
}

// ---------------------------------------------------------------------------
// 128x128 GEMM core, B^T form, BK=32, m97 structure (R7-verified).
// ---------------------------------------------------------------------------
__device__ __forceinline__ void gemm_core_128x128(
    const bf16_t* __restrict__ A, const bf16_t* __restrict__ Bt, int K,
    bf16_t* __restrict__ sA, bf16_t* __restrict__ sB, floatx4 acc[4][4]) {
  const int tid = threadIdx.x;
  const int lane = tid & 63;
  const int w = tid >> 6;
  const int quad = lane >> 4;
  const int l16 = lane & 15;
  const int wm = w >> 1;
  const int wn = w & 1;
  const int sr = tid >> 2;
  const int sc = (tid & 3) * 8;
  const int wbase = w * 512;

  const bf16_t* pa0 = A + (size_t)sr * K + sc;
  const bf16_t* pa1 = A + (size_t)(sr + 64) * K + sc;
  const bf16_t* pb0 = Bt + (size_t)sr * K + sc;
  const bf16_t* pb1 = Bt + (size_t)(sr + 64) * K + sc;

  for (int kk = 0; kk < K; kk += 32) {
    __syncthreads();
    gl_lds16(pa0 + kk, sA + wbase);
    gl_lds16(pa1 + kk, sA + 2048 + wbase);
    gl_lds16(pb0 + kk, sB + wbase);
    gl_lds16(pb1 + kk, sB + 2048 + wbase);
    __syncthreads();
    bf16x8 af[4], bf[4];
#pragma unroll
    for (int mi = 0; mi < 4; mi++)
      af[mi] = *(const bf16x8*)(sA + (wm * 64 + mi * 16 + l16) * 32 + quad * 8);
#pragma unroll
    for (int ni = 0; ni < 4; ni++)
      bf[ni] = *(const bf16x8*)(sB + (wn * 64 + ni * 16 + l16) * 32 + quad * 8);
#pragma unroll
    for (int mi = 0; mi < 4; mi++)
#pragma unroll
      for (int ni = 0; ni < 4; ni++)
        acc[mi][ni] = MFMA_BF16_16x16x32(af[mi], bf[ni], acc[mi][ni]);
  }
}

// ---------------------------------------------------------------------------
// 64x128 GEMM core, BK=32 (out_proj, R7-verified).
// ---------------------------------------------------------------------------
__device__ __forceinline__ void gemm_core_64x128(
    const bf16_t* __restrict__ A, const bf16_t* __restrict__ Bt, int K,
    bf16_t* __restrict__ sA, bf16_t* __restrict__ sB, floatx4 acc[2][4]) {
  const int tid = threadIdx.x;
  const int lane = tid & 63;
  const int w = tid >> 6;
  const int quad = lane >> 4;
  const int l16 = lane & 15;
  const int wm = w >> 1;
  const int wn = w & 1;
  const int sr = tid >> 2;
  const int sc = (tid & 3) * 8;
  const int wbase = w * 512;

  const bf16_t* pa = A + (size_t)sr * K + sc;
  const bf16_t* pb0 = Bt + (size_t)sr * K + sc;
  const bf16_t* pb1 = Bt + (size_t)(sr + 64) * K + sc;

  for (int kk = 0; kk < K; kk += 32) {
    __syncthreads();
    gl_lds16(pa + kk, sA + wbase);
    gl_lds16(pb0 + kk, sB + wbase);
    gl_lds16(pb1 + kk, sB + 2048 + wbase);
    __syncthreads();
    bf16x8 af[2], bf[4];
#pragma unroll
    for (int mi = 0; mi < 2; mi++)
      af[mi] = *(const bf16x8*)(sA + (wm * 32 + mi * 16 + l16) * 32 + quad * 8);
#pragma unroll
    for (int ni = 0; ni < 4; ni++)
      bf[ni] = *(const bf16x8*)(sB + (wn * 64 + ni * 16 + l16) * 32 + quad * 8);
#pragma unroll
    for (int mi = 0; mi < 2; mi++)
#pragma unroll
      for (int ni = 0; ni < 4; ni++)
        acc[mi][ni] = MFMA_BF16_16x16x32(af[mi], bf[ni], acc[mi][ni]);
  }
}

// ---------------------------------------------------------------------------
// QKV projection. ALL outputs in MFMA fragment order (R7-verified):
//   Qf[bh][task][kh][lane][8], Kf[bh][kt][kh][ni][lane][8],
//   Vf[bh][kt][ks][nd][lane][8].
// grid = (8, 32, 3)
// ---------------------------------------------------------------------------
__global__ __launch_bounds__(256) void qkv_proj(
    const bf16_t* __restrict__ x, const bf16_t* __restrict__ wt_base,
    bf16_t* __restrict__ Qf, bf16_t* __restrict__ Kf, bf16_t* __restrict__ Vf) {
  __shared__ bf16_t smem[8704];  // staging 8192; epilogue 4 waves x 2176
  const int n0 = blockIdx.x * 128;
  const int m0 = blockIdx.y * 128;
  const int which = blockIdx.z;
  const bf16_t* Bt = wt_base + (size_t)which * (kDM * kDM);

  floatx4 acc[4][4];
  const floatx4 zero4 = {0.f, 0.f, 0.f, 0.f};
#pragma unroll
  for (int mi = 0; mi < 4; mi++)
#pragma unroll
    for (int ni = 0; ni < 4; ni++) acc[mi][ni] = zero4;

  gemm_core_128x128(x + (size_t)m0 * kDM, Bt + (size_t)n0 * kDM, kDM,
                    smem, smem + 4096, acc);

  const int tid = threadIdx.x;
  const int lane = tid & 63, w = tid >> 6;
  const int quad = lane >> 4, l16 = lane & 15;
  const int wm = w >> 1, wn = w & 1;
  const int h = (n0 + wn * 64) >> 6;  // this wave's head

  if (which == 2) {
    // V: direct stores (512B-coalesced per instruction)
#pragma unroll
    for (int mi = 0; mi < 4; mi++) {
#pragma unroll
      for (int ni = 0; ni < 4; ni++) {
        const int n = n0 + wn * 64 + ni * 16 + l16;
        const int d = n & 63;
        const int ndv = d >> 4, l16v = d & 15;
        const int m = m0 + wm * 64 + mi * 16 + quad * 4;  // reg 0 row
        const int b = m >> 11, t0 = m & (kT - 1);
        const int kt = t0 >> 7, ks = (t0 >> 5) & 3, quadv = (t0 >> 3) & 3;
        const int eb = t0 & 4;
        bf16x4 v;
        v[0] = (bf16_t)acc[mi][ni][0];
        v[1] = (bf16_t)acc[mi][ni][1];
        v[2] = (bf16_t)acc[mi][ni][2];
        v[3] = (bf16_t)acc[mi][ni][3];
        *(bf16x4*)(Vf + (((((size_t)(b * kNH + h) * 16 + kt) * 4 + ks) * 4 +
                          ndv) * 64 + quadv * 16 + l16v) * 8 + eb) = v;
      }
    }
  } else {
    __syncthreads();  // staging-LDS readers done before reuse
    bf16_t* Out = (which == 0) ? Qf : Kf;
    bf16_t* Lw = smem + w * 2176;  // wave-private: 32 rows x 68 stride
#pragma unroll
    for (int pass = 0; pass < 2; pass++) {
#pragma unroll
      for (int mi2 = 0; mi2 < 2; mi2++) {
        const int mi = pass * 2 + mi2;
#pragma unroll
        for (int ni = 0; ni < 4; ni++)
#pragma unroll
          for (int reg = 0; reg < 4; reg++)
            Lw[(mi2 * 16 + quad * 4 + reg) * 68 + ni * 16 + l16] =
                (bf16_t)acc[mi][ni][reg];
      }
      __asm volatile("s_waitcnt lgkmcnt(0)" ::: "memory");
      const int tb = m0 + wm * 64 + pass * 32;  // uniform
#pragma unroll
      for (int i = 0; i < 4; i++) {
        const int khf = i >> 1, nifr = i & 1;
        const bf16x8 v = *(const bf16x8*)(Lw + (nifr * 16 + l16) * 68 +
                                          khf * 32 + quad * 8);
        const int t0 = tb + nifr * 16;  // uniform, multiple of 16
        const int b = t0 >> 11, tt = t0 & (kT - 1);
        size_t base;
        if (which == 0) {
          base = (((size_t)(b * kNH + h) * 128 + (tt >> 4)) * 2 + khf) * 512;
        } else {
          const int kt = tt >> 7, nif = (tt & 127) >> 4;
          base = ((((size_t)(b * kNH + h) * 16 + kt) * 2 + khf) * 8 + nif) * 512;
        }
        *(bf16x8*)(Out + base + lane * 8) = v;  // 1KB contiguous per wave
      }
    }
  }
}

// ---------------------------------------------------------------------------
// One attention wave-task: 16 q-rows, causal, static-max softmax
// p = exp2(s*C1 - 16) via raw v_exp_f32. Main loop is MASK-FREE; the
// diagonal k-tile is peeled (only it needs the causal mask, and it skips the
// K-prefetch). Fragment-order Q/K/V loads (base + lane*16B). No barriers:
// P region in LDS is wave-private (in-order DS pipe + lgkmcnt fence).
// ---------------------------------------------------------------------------
__device__ __forceinline__ void attn_task(
    int task, int lane, int l16, int quad, const bf16_t* __restrict__ Qb,
    const bf16_t* __restrict__ Kbf, const bf16_t* __restrict__ Vbf,
    bf16_t* __restrict__ Pw, bf16_t* __restrict__ Z, int b, int h) {
  const int q0 = task * 16;
  const int nkt = (task >> 3) + 1;
  const float C1 = 0.125f * kLog2e;

  bf16x8 qf[2];
#pragma unroll
  for (int kh = 0; kh < 2; kh++)
    qf[kh] = *(const bf16x8*)(Qb + ((size_t)task * 2 + kh) * 512 + lane * 8);

  const floatx4 zero4 = {0.f, 0.f, 0.f, 0.f};
  floatx4 of[4];
  float lrow[4];
#pragma unroll
  for (int nd = 0; nd < 4; nd++) of[nd] = zero4;
#pragma unroll
  for (int r = 0; r < 4; r++) lrow[r] = 0.f;

  // preload K fragments for kt = 0 (frag stride 512 elem = 1KB burst)
  bf16x8 kf[16];
#pragma unroll
  for (int fi = 0; fi < 16; fi++)
    kf[fi] = *(const bf16x8*)(Kbf + (size_t)fi * 512 + lane * 8);

  // ---- main loop: k-tiles strictly below the diagonal (no mask) ----
  for (int kt = 0; kt < nkt - 1; kt++) {
    floatx4 sf[8];
#pragma unroll
    for (int ni = 0; ni < 8; ni++) sf[ni] = zero4;
#pragma unroll
    for (int kh = 0; kh < 2; kh++)
#pragma unroll
      for (int ni = 0; ni < 8; ni++)
        sf[ni] = MFMA_BF16_16x16x32(qf[kh], kf[kh * 8 + ni], sf[ni]);
    // prefetch next K tile (kt+1 <= nkt-1 always valid here)
    const bf16_t* kp = Kbf + (size_t)(kt + 1) * 16 * 512 + lane * 8;
#pragma unroll
    for (int fi = 0; fi < 16; fi++)
      kf[fi] = *(const bf16x8*)(kp + (size_t)fi * 512);
    // V fragments for current tile (latency hidden by softmax)
    const bf16_t* vp = Vbf + (size_t)kt * 16 * 512 + lane * 8;
    bf16x8 vf[16];
#pragma unroll
    for (int fi = 0; fi < 16; fi++)
      vf[fi] = *(const bf16x8*)(vp + (size_t)fi * 512);
    // mask-free softmax
#pragma unroll
    for (int reg = 0; reg < 4; reg++) {
      const int row_l = quad * 4 + reg;
      float rsum = 0.f;
#pragma unroll
      for (int ni = 0; ni < 8; ni++) {
        const float p = __builtin_amdgcn_exp2f(sf[ni][reg] * C1 - 16.f);
        rsum += p;
        Pw[row_l * kPS + ni * 16 + l16] = (bf16_t)p;
      }
      lrow[reg] += rsum;
    }
    __asm volatile("s_waitcnt lgkmcnt(0)" ::: "memory");
#pragma unroll
    for (int ks = 0; ks < 4; ks++) {
      const bf16x8 af = *(const bf16x8*)(Pw + l16 * kPS + ks * 32 + quad * 8);
#pragma unroll
      for (int nd = 0; nd < 4; nd++)
        of[nd] = MFMA_BF16_16x16x32(af, vf[ks * 4 + nd], of[nd]);
    }
  }

  // ---- peeled diagonal k-tile (kt = nkt-1): causal mask, no K-prefetch ----
  {
    const int kt = nkt - 1;
    const int kbase = kt * 128;
    floatx4 sf[8];
#pragma unroll
    for (int ni = 0; ni < 8; ni++) sf[ni] = zero4;
#pragma unroll
    for (int kh = 0; kh < 2; kh++)
#pragma unroll
      for (int ni = 0; ni < 8; ni++)
        sf[ni] = MFMA_BF16_16x16x32(qf[kh], kf[kh * 8 + ni], sf[ni]);
    const bf16_t* vp = Vbf + (size_t)kt * 16 * 512 + lane * 8;
    bf16x8 vf[16];
#pragma unroll
    for (int fi = 0; fi < 16; fi++)
      vf[fi] = *(const bf16x8*)(vp + (size_t)fi * 512);
#pragma unroll
    for (int reg = 0; reg < 4; reg++) {
      const int row_l = quad * 4 + reg;
      const int row_g = q0 + row_l;
      float rsum = 0.f;
#pragma unroll
      for (int ni = 0; ni < 8; ni++) {
        float s = sf[ni][reg] * C1 - 16.f;
        if (kbase + ni * 16 + l16 > row_g) s = -3.0e38f;
        const float p = __builtin_amdgcn_exp2f(s);
        rsum += p;
        Pw[row_l * kPS + ni * 16 + l16] = (bf16_t)p;
      }
      lrow[reg] += rsum;
    }
    __asm volatile("s_waitcnt lgkmcnt(0)" ::: "memory");
#pragma unroll
    for (int ks = 0; ks < 4; ks++) {
      const bf16x8 af = *(const bf16x8*)(Pw + l16 * kPS + ks * 32 + quad * 8);
#pragma unroll
      for (int nd = 0; nd < 4; nd++)
        of[nd] = MFMA_BF16_16x16x32(af, vf[ks * 4 + nd], of[nd]);
    }
  }

  // ---- epilogue: reduce l across 16 lanes, then Z = O / l ----
#pragma unroll
  for (int reg = 0; reg < 4; reg++) {
#pragma unroll
    for (int off = 1; off < 16; off <<= 1)
      lrow[reg] += __shfl_xor(lrow[reg], off, 64);
  }
#pragma unroll
  for (int reg = 0; reg < 4; reg++) {
    const int t = q0 + quad * 4 + reg;
    const float inv = 1.f / lrow[reg];
#pragma unroll
    for (int nd = 0; nd < 4; nd++) {
      const int col = h * 64 + nd * 16 + l16;
      Z[(size_t)(b * kT + t) * kDM + col] = (bf16_t)(of[nd][reg] * inv);
    }
  }
}

// ---------------------------------------------------------------------------
// Flash attention (causal), wave-independent, exactly-balanced (R7 skeleton).
// grid = (B*H=32, 16): blockIdx.x = bh -> XCD locality. Wave handles task
// pair (i, 127-i): exactly 17 k-tiles each. No barriers.
// ---------------------------------------------------------------------------
__global__ __launch_bounds__(256, 2) void attn_fused(
    const bf16_t* __restrict__ Qf, const bf16_t* __restrict__ Kf,
    const bf16_t* __restrict__ Vf, bf16_t* __restrict__ Z) {
  __shared__ bf16_t Ps[64 * kPS];
  const int bh = blockIdx.x;
  const int tid = threadIdx.x;
  const int lane = tid & 63;
  const int w = tid >> 6;
  const int quad = lane >> 4;
  const int l16 = lane & 15;
  const int pairidx = blockIdx.y * 4 + w;  // 0..63
  bf16_t* Pw = Ps + (w * 16) * kPS;

  const bf16_t* Qb = Qf + (size_t)bh * kT * kDH;
  const bf16_t* Kbf = Kf + (size_t)bh * kT * kDH;
  const bf16_t* Vbf = Vf + (size_t)bh * kT * kDH;
  const int b = bh >> 4, h = bh & 15;

  attn_task(pairidx, lane, l16, quad, Qb, Kbf, Vbf, Pw, Z, b, h);
  attn_task(127 - pairidx, lane, l16, quad, Qb, Kbf, Vbf, Pw, Z, b, h);
}

// ---------------------------------------------------------------------------
// Output projection: Z [4096][1024] @ Wout^T -> out (dtype per flag).
// 64x128 tiles, BK=32: grid (8, 64) = 512 blocks = 2 blocks/CU.
// ---------------------------------------------------------------------------
__global__ __launch_bounds__(256) void out_proj(
    const bf16_t* __restrict__ Zin, const bf16_t* __restrict__ WtO,
    void* __restrict__ out, const int* __restrict__ flagp) {
  __shared__ bf16_t smem[6144];  // sA 2048 + sB 4096
  const int f = *flagp;
  const int n0 = blockIdx.x * 128;
  const int m0 = blockIdx.y * 64;
  floatx4 acc[2][4];
  const floatx4 zero4 = {0.f, 0.f, 0.f, 0.f};
#pragma unroll
  for (int mi = 0; mi < 2; mi++)
#pragma unroll
    for (int ni = 0; ni < 4; ni++) acc[mi][ni] = zero4;

  gemm_core_64x128(Zin + (size_t)m0 * kDM, WtO + (size_t)n0 * kDM, kDM,
                   smem, smem + 2048, acc);

  const int tid = threadIdx.x;
  const int lane = tid & 63, w = tid >> 6;
  const int quad = lane >> 4, l16 = lane & 15;
  const int wm = w >> 1, wn = w & 1;
#pragma unroll
  for (int mi = 0; mi < 2; mi++) {
#pragma unroll
    for (int ni = 0; ni < 4; ni++) {
      const int n = n0 + wn * 64 + ni * 16 + l16;
#pragma unroll
      for (int reg = 0; reg < 4; reg++) {
        const int m = m0 + wm * 32 + mi * 16 + quad * 4 + reg;
        if (f) {
          ((bf16_t*)out)[(size_t)m * kDM + n] = (bf16_t)acc[mi][ni][reg];
        } else {
          ((float*)out)[(size_t)m * kDM + n] = acc[mi][ni][reg];
        }
      }
    }
  }
}

// ---------------------------------------------------------------------------
// Workspace layout (bf16 elements):
//   [0,4M)   : W^T q,k,v,o   (4 x 1M)
//   [4M,8M)  : xb (x as bf16)
//   [8M,12M) : Qf fragment-order
//   [12M,16M): Kf fragment-order
//   [16M,20M): Vf fragment-order
//   [20M,24M): Z  [B][T][H*D]
//   [24M]    : dtype flag
// ---------------------------------------------------------------------------
extern "C" void kernel_launch(void* const* d_in, const int* in_sizes, int n_in,
                              void* d_out, int out_size, void* d_ws,
                              size_t ws_size, hipStream_t stream) {
  const void* x = d_in[0];
  const void* Wq = d_in[1];
  const void* Wk = d_in[2];
  const void* Wv = d_in[3];
  const void* Wo = d_in[4];
  bf16_t* ws = (bf16_t*)d_ws;
  const size_t MEG = 1024 * 1024;
  bf16_t* wt = ws;
  bf16_t* xb = ws + 4 * MEG;
  bf16_t* Qf = ws + 8 * MEG;
  bf16_t* Kf = ws + 12 * MEG;
  bf16_t* Vf = ws + 16 * MEG;
  bf16_t* Z = ws + 20 * MEG;
  int* flagp = (int*)(ws + 24 * MEG);

  detect_dtype<<<1, 256, 0, stream>>>((const unsigned short*)x, flagp);
  convert_x<<<2048, 256, 0, stream>>>(x, xb, flagp, 4 * (int)MEG);
  convert_transpose_w<<<dim3(16, 16, 4), 256, 0, stream>>>(Wq, Wk, Wv, Wo, wt,
                                                           flagp);
  qkv_proj<<<dim3(8, 32, 3), 256, 0, stream>>>(xb, wt, Qf, Kf, Vf);
  attn_fused<<<dim3(32, 16), 256, 0, stream>>>(Qf, Kf, Vf, Z);
  out_proj<<<dim3(8, 64), 256, 0, stream>>>(Z, wt + 3 * MEG, d_out, flagp);
}